// Round 1
// baseline (2486.938 us; speedup 1.0000x reference)
//
#include <hip/hip_runtime.h>

// ECGLSTM: B=256 seqs, T=5000 steps, input_size=1, H=64, fused FC(64->128)+ReLU.
// One block per batch element; thread j (0..255) owns gate j (W_hh row j in VGPRs).
// Waves are gate-type-uniform: wave0=i(sig), wave1=f(sig), wave2=g(tanh), wave3=o(sig).
// h broadcast via LDS (same-address reads = free broadcast); 2 barriers/step.

#define LSTM_H 64
#define LSTM_T 5000
#define LSTM_B 256
#define XCHUNK 256

__device__ __forceinline__ float fast_rcp(float v) {
    return __builtin_amdgcn_rcpf(v);
}

__global__ __launch_bounds__(256) void ECGLSTM_lstm_fused(
    const float* __restrict__ x,      // [B, T]
    const float* __restrict__ W_ih,   // [4H, 1]
    const float* __restrict__ W_hh,   // [4H, H]
    const float* __restrict__ b_ih,   // [4H]
    const float* __restrict__ b_hh,   // [4H]
    const float* __restrict__ W_fc,   // [128, H]
    const float* __restrict__ b_fc,   // [128]
    float* __restrict__ out)          // [B, 128]
{
    const int tid = threadIdx.x;      // gate index 0..255
    const int b   = blockIdx.x;       // batch element

    __shared__ float h_lds[LSTM_H];
    __shared__ float gates[4 * LSTM_H];
    __shared__ float xch[XCHUNK];

    // W_hh row `tid` -> registers (64 floats, 16x float4)
    float w[LSTM_H];
    {
        const float4* wrow = reinterpret_cast<const float4*>(W_hh + tid * LSTM_H);
        #pragma unroll
        for (int i = 0; i < LSTM_H / 4; ++i) {
            float4 v = wrow[i];
            w[4*i+0] = v.x; w[4*i+1] = v.y; w[4*i+2] = v.z; w[4*i+3] = v.w;
        }
    }
    const float wih  = W_ih[tid];
    const float bias = b_ih[tid] + b_hh[tid];
    const bool  is_tanh = ((tid >> 6) == 2);   // wave-uniform

    float c = 0.0f;                    // cell state lives in threads 0..63
    if (tid < LSTM_H) h_lds[tid] = 0.0f;
    __syncthreads();

    const float* xb = x + b * LSTM_T;

    for (int base = 0; base < LSTM_T; base += XCHUNK) {
        const int nt = (LSTM_T - base < XCHUNK) ? (LSTM_T - base) : XCHUNK;
        if (tid < nt) xch[tid] = xb[base + tid];
        __syncthreads();

        for (int tt = 0; tt < nt; ++tt) {
            const float xv = xch[tt];

            // gate_j = bias + x*wih + sum_k h[k] * W_hh[j][k]
            float a0 = 0.f, a1 = 0.f, a2 = 0.f, a3 = 0.f;
            const float4* h4 = reinterpret_cast<const float4*>(h_lds);
            #pragma unroll
            for (int i = 0; i < LSTM_H / 4; ++i) {
                float4 hv = h4[i];                 // ds_read_b128, broadcast
                a0 = fmaf(hv.x, w[4*i+0], a0);
                a1 = fmaf(hv.y, w[4*i+1], a1);
                a2 = fmaf(hv.z, w[4*i+2], a2);
                a3 = fmaf(hv.w, w[4*i+3], a3);
            }
            float g = fmaf(xv, wih, bias) + ((a0 + a1) + (a2 + a3));

            float act;
            if (is_tanh) {
                // tanh(g) = 1 - 2/(exp(2g)+1)
                float e = __expf(2.0f * g);
                act = 1.0f - 2.0f * fast_rcp(e + 1.0f);
            } else {
                // sigmoid(g) = 1/(1+exp(-g))
                float e = __expf(-g);
                act = fast_rcp(1.0f + e);
            }
            gates[tid] = act;
            __syncthreads();

            if (tid < LSTM_H) {
                float ig = gates[tid];
                float fg = gates[LSTM_H + tid];
                float gg = gates[2 * LSTM_H + tid];
                float og = gates[3 * LSTM_H + tid];
                c = fmaf(fg, c, ig * gg);
                float e  = __expf(2.0f * c);
                float th = 1.0f - 2.0f * fast_rcp(e + 1.0f);
                h_lds[tid] = og * th;
            }
            __syncthreads();
        }
    }

    // FC head: out[b][j] = relu(b_fc[j] + sum_k h[k] * W_fc[j][k]), j<128
    if (tid < 128) {
        float s = b_fc[tid];
        const float* wf = W_fc + tid * LSTM_H;
        #pragma unroll
        for (int k = 0; k < LSTM_H; ++k) s = fmaf(h_lds[k], wf[k], s);
        out[b * 128 + tid] = fmaxf(s, 0.0f);
    }
}

extern "C" void kernel_launch(void* const* d_in, const int* in_sizes, int n_in,
                              void* d_out, int out_size, void* d_ws, size_t ws_size,
                              hipStream_t stream) {
    const float* x    = (const float*)d_in[0];
    const float* W_ih = (const float*)d_in[1];
    const float* W_hh = (const float*)d_in[2];
    const float* b_ih = (const float*)d_in[3];
    const float* b_hh = (const float*)d_in[4];
    const float* W_fc = (const float*)d_in[5];
    const float* b_fc = (const float*)d_in[6];
    float* out = (float*)d_out;

    ECGLSTM_lstm_fused<<<LSTM_B, 256, 0, stream>>>(
        x, W_ih, W_hh, b_ih, b_hh, W_fc, b_fc, out);
}